// Round 2
// baseline (48.161 us; speedup 1.0000x reference)
//
#include <hip/hip_runtime.h>
#include <hip/hip_bf16.h>

// DomainBatchNorm: out[b,f] = x[b,f] * scale[d(b),f] + shift[d(b),f]
// Two-kernel plan:
//   k1 (tiny): fold scale = gamma*rsqrt(var+eps), shift = beta - mean*scale
//              into d_ws (2 x 32 KB, L2-resident).
//   k2: wave-per-row apply. Per wave: resolve domain via __ballot over
//       lanes 0..7 (no LDS, no barrier), then 4 x {load scale,shift,x ->
//       fma -> NONTEMPORAL store}. nt store keeps x resident in the 256MB
//       L3 across graph replays.

#define F_DIM 1024
#define D_DIM 8
#define EPSV  1e-5f

typedef float f4 __attribute__((ext_vector_type(4)));

__global__ __launch_bounds__(256) void dbn_fold(
    const f4* __restrict__ gammas, const f4* __restrict__ betas,
    const f4* __restrict__ means,  const f4* __restrict__ vars,
    f4* __restrict__ scale, f4* __restrict__ shift)
{
    const int i = blockIdx.x * 256 + threadIdx.x;   // 0 .. D*F/4-1 (2048)
    if (i >= D_DIM * (F_DIM / 4)) return;
    f4 g = gammas[i], b = betas[i], m = means[i], v = vars[i];
    f4 s, h;
    s.x = g.x * rsqrtf(v.x + EPSV); h.x = fmaf(-m.x, s.x, b.x);
    s.y = g.y * rsqrtf(v.y + EPSV); h.y = fmaf(-m.y, s.y, b.y);
    s.z = g.z * rsqrtf(v.z + EPSV); h.z = fmaf(-m.z, s.z, b.z);
    s.w = g.w * rsqrtf(v.w + EPSV); h.w = fmaf(-m.w, s.w, b.w);
    scale[i] = s; shift[i] = h;
}

// One wave (64 lanes) per row; 4 waves per block. Lane l handles float4
// columns l, l+64, l+128, l+192 (coalesced 16B/lane).
__global__ __launch_bounds__(256) void dbn_apply(
    const f4* __restrict__ x, const float* __restrict__ mask,
    const f4* __restrict__ scale, const f4* __restrict__ shift,
    f4* __restrict__ out, int B)
{
    const int wave = threadIdx.x >> 6;
    const int lane = threadIdx.x & 63;
    const int row  = (blockIdx.x << 2) | wave;
    if (row >= B) return;  // wave-uniform exit

    // Domain resolve: lanes 0..7 test the one-hot mask; ballot -> ffs.
    float mv = (lane < D_DIM) ? mask[(size_t)row * D_DIM + lane] : 0.0f;
    unsigned long long bal = __ballot(mv > 0.5f);
    const int d = __ffsll(bal) - 1;

    const f4* __restrict__ sc = scale + (size_t)d * (F_DIM / 4);
    const f4* __restrict__ sh = shift + (size_t)d * (F_DIM / 4);
    const f4* __restrict__ xr = x     + (size_t)row * (F_DIM / 4);
    f4* __restrict__ orow     = out   + (size_t)row * (F_DIM / 4);

    #pragma unroll
    for (int k = 0; k < 4; ++k) {
        const int c = lane + (k << 6);
        f4 s = sc[c], h = sh[c], xv = xr[c];
        f4 o;
        o.x = fmaf(xv.x, s.x, h.x);
        o.y = fmaf(xv.y, s.y, h.y);
        o.z = fmaf(xv.z, s.z, h.z);
        o.w = fmaf(xv.w, s.w, h.w);
        __builtin_nontemporal_store(o, &orow[c]);
    }
}

// Fallback (ws too small): wave-per-row with inline fold, nt stores.
__global__ __launch_bounds__(256) void dbn_apply_inline(
    const f4* __restrict__ x, const float* __restrict__ mask,
    const f4* __restrict__ gammas, const f4* __restrict__ betas,
    const f4* __restrict__ means,  const f4* __restrict__ vars,
    f4* __restrict__ out, int B)
{
    const int wave = threadIdx.x >> 6;
    const int lane = threadIdx.x & 63;
    const int row  = (blockIdx.x << 2) | wave;
    if (row >= B) return;

    float mv = (lane < D_DIM) ? mask[(size_t)row * D_DIM + lane] : 0.0f;
    unsigned long long bal = __ballot(mv > 0.5f);
    const int d = __ffsll(bal) - 1;

    const size_t pb = (size_t)d * (F_DIM / 4);
    const f4* __restrict__ xr = x + (size_t)row * (F_DIM / 4);
    f4* __restrict__ orow     = out + (size_t)row * (F_DIM / 4);

    #pragma unroll
    for (int k = 0; k < 4; ++k) {
        const int c = lane + (k << 6);
        f4 g = gammas[pb + c], b = betas[pb + c], m = means[pb + c], v = vars[pb + c];
        f4 xv = xr[c];
        f4 o; float s;
        s = g.x * rsqrtf(v.x + EPSV); o.x = fmaf(xv.x, s, fmaf(-m.x, s, b.x));
        s = g.y * rsqrtf(v.y + EPSV); o.y = fmaf(xv.y, s, fmaf(-m.y, s, b.y));
        s = g.z * rsqrtf(v.z + EPSV); o.z = fmaf(xv.z, s, fmaf(-m.z, s, b.z));
        s = g.w * rsqrtf(v.w + EPSV); o.w = fmaf(xv.w, s, fmaf(-m.w, s, b.w));
        __builtin_nontemporal_store(o, &orow[c]);
    }
}

extern "C" void kernel_launch(void* const* d_in, const int* in_sizes, int n_in,
                              void* d_out, int out_size, void* d_ws, size_t ws_size,
                              hipStream_t stream) {
    const float* x    = (const float*)d_in[0];
    const float* mask = (const float*)d_in[1];
    const float* gam  = (const float*)d_in[2];
    const float* bet  = (const float*)d_in[3];
    const float* mu   = (const float*)d_in[4];
    const float* var  = (const float*)d_in[5];
    float* out        = (float*)d_out;

    const int B = in_sizes[0] / F_DIM;             // 32768
    const int grid = (B + 3) / 4;                  // 4 rows (waves) per block

    const size_t fold_bytes = (size_t)2 * D_DIM * F_DIM * sizeof(float); // 64 KB

    if (ws_size >= fold_bytes) {
        f4* scale = (f4*)d_ws;
        f4* shift = (f4*)((char*)d_ws + fold_bytes / 2);
        const int n_fold = D_DIM * (F_DIM / 4);    // 2048
        dbn_fold<<<(n_fold + 255) / 256, 256, 0, stream>>>(
            (const f4*)gam, (const f4*)bet, (const f4*)mu, (const f4*)var,
            scale, shift);
        dbn_apply<<<grid, 256, 0, stream>>>(
            (const f4*)x, mask, scale, shift, (f4*)out, B);
    } else {
        dbn_apply_inline<<<grid, 256, 0, stream>>>(
            (const f4*)x, mask, (const f4*)gam, (const f4*)bet,
            (const f4*)mu, (const f4*)var, (f4*)out, B);
    }
}